// Round 7
// baseline (14839.981 us; speedup 1.0000x reference)
//
#include <hip/hip_runtime.h>
#include <hip/hip_bf16.h>
#include <stdint.h>

// Problem constants
#define TT 256
#define BB 64
#define DIN 512
#define RR 2048
#define DOUT 128
#define NTOT (RR*RR)                // 4194304
#define NKEEP 838860                // int(4194304 * (1.0 - 0.8)) in IEEE double
#define BETA 0.9f
#define VTH 1.0f

// ---------------- workspace layout ----------------
// drive : float [16384][2048]   @ 0            (134217728 B)
// mask  : u64   [256][64][32]   @ 134217728    (4 MB)   spike bits per (t,b), u64 per wave
// flags : u32   [256][64]       @ +4MB         (64 KB)  32 producer bits per (t,b)
// hist  : u32   [256]
// state : u32   [8]   (0: prefix, 1: remaining, 2: thresh bits)
// cnts  : u32   [2]   (0: spike count, 1: active count)
// NOTE: w_rec is masked AND group-XOR-swizzled IN PLACE (inputs restored each launch).
//       Row r: 64-col group g's data lives at group g ^ (r & 31)  (involution).

__global__ void k_init(uint32_t* __restrict__ p, int n) {
    int i = blockIdx.x * blockDim.x + threadIdx.x;
    int stride = gridDim.x * blockDim.x;
    for (; i < n; i += stride) p[i] = 0u;
}

// ---------------- radix select (4 passes x 8 bits, k-th largest) ----------------
__global__ void k_hist(const float* __restrict__ w_rec, uint32_t* __restrict__ hist,
                       const uint32_t* __restrict__ state, int p) {
    __shared__ uint32_t lh[256];
    lh[threadIdx.x] = 0u;
    __syncthreads();
    uint32_t prefix = (p > 0) ? state[0] : 0u;
    int sh = 24 - 8 * p;
    int i = blockIdx.x * 256 + threadIdx.x;
    int stride = gridDim.x * 256;
    for (; i < NTOT; i += stride) {
        uint32_t u = __float_as_uint(fabsf(w_rec[i]));
        bool ok = (p == 0) || ((u >> (sh + 8)) == prefix);
        if (ok) atomicAdd(&lh[(u >> sh) & 255u], 1u);
    }
    __syncthreads();
    uint32_t v = lh[threadIdx.x];
    if (v) atomicAdd(&hist[threadIdx.x], v);
}

__global__ void k_select(uint32_t* __restrict__ hist, uint32_t* __restrict__ state, int p) {
    __shared__ uint32_t lh[256];
    int tid = threadIdx.x;
    lh[tid] = hist[tid];
    hist[tid] = 0u;            // ready for next pass
    __syncthreads();
    if (tid == 0) {
        uint32_t remaining = (p == 0) ? (uint32_t)NKEEP : state[1];
        int bin = 255;
        for (; bin > 0; --bin) {
            uint32_t c = lh[bin];
            if (c >= remaining) break;
            remaining -= c;
        }
        uint32_t pref = (p == 0) ? 0u : state[0];
        pref = (pref << 8) | (uint32_t)bin;
        state[0] = pref;
        state[1] = remaining;
        if (p == 3) state[2] = pref;   // full 32-bit pattern of threshold value
    }
}

// ---------------- fused: mask + XOR-group-swizzle w_rec in place + count actives ------
// Row r, swap mask m = r & 31. Pairs (g, g^m) swapped (g has MSB(m) bit clear).
// Channel-camping fix: gather addresses then vary L2-channel bits with row.
__global__ __launch_bounds__(1024) void k_swz(float* __restrict__ w,
                                              const uint32_t* __restrict__ state,
                                              uint32_t* __restrict__ cnts) {
    const int r = blockIdx.x;          // row 0..2047
    const uint32_t th = state[2];
    const int m = r & 31;
    const int tid = threadIdx.x;       // 0..1023
    uint32_t c = 0;
    if (m == 0) {
        for (int k = tid; k < RR; k += 1024) {
            float v = w[(size_t)r * RR + k];
            if ((__float_as_uint(v) & 0x7fffffffu) >= th) c++;
            else w[(size_t)r * RR + k] = 0.0f;
        }
    } else {
        const int h = 31 - __clz(m);   // MSB index of m
        const int p = tid >> 6;        // pair index 0..15
        const int lane = tid & 63;
        const int g = ((p >> h) << (h + 1)) | (p & ((1 << h) - 1));   // bit h clear
        const int g2 = g ^ m;
        const size_t i1 = (size_t)r * RR + (g << 6) + lane;
        const size_t i2 = (size_t)r * RR + (g2 << 6) + lane;
        float v1 = w[i1], v2 = w[i2];
        if ((__float_as_uint(v1) & 0x7fffffffu) >= th) c++; else v1 = 0.0f;
        if ((__float_as_uint(v2) & 0x7fffffffu) >= th) c++; else v2 = 0.0f;
        w[i1] = v2;                    // involution swap
        w[i2] = v1;
    }
    for (int off = 32; off > 0; off >>= 1) c += __shfl_down(c, off);
    if ((tid & 63) == 0 && c) atomicAdd(&cnts[1], c);
}

// ---------------- drive GEMM: [16384,512] x [512,2048] + b_in ----------------
__global__ __launch_bounds__(256) void k_drive(const float* __restrict__ x,
                                               const float* __restrict__ w_in,
                                               const float* __restrict__ b_in,
                                               float* __restrict__ drive) {
    __shared__ float As[8][128];
    __shared__ float Bs[8][128];
    const int m0 = blockIdx.x * 128;
    const int n0 = blockIdx.y * 128;
    const int tid = threadIdx.x;
    const int tx = tid & 15, ty = tid >> 4;
    const int ar = tid >> 1;
    const int ak = (tid & 1) * 4;
    const int bk = tid >> 5;
    const int bc = (tid & 31) * 4;
    float acc[8][8];
    #pragma unroll
    for (int i = 0; i < 8; ++i)
        #pragma unroll
        for (int j = 0; j < 8; ++j) acc[i][j] = 0.0f;

    for (int k0 = 0; k0 < DIN; k0 += 8) {
        float4 av = *(const float4*)&x[(m0 + ar) * DIN + k0 + ak];
        float4 bv = *(const float4*)&w_in[(size_t)(k0 + bk) * RR + n0 + bc];
        __syncthreads();
        As[ak + 0][ar] = av.x; As[ak + 1][ar] = av.y;
        As[ak + 2][ar] = av.z; As[ak + 3][ar] = av.w;
        *(float4*)&Bs[bk][bc] = bv;
        __syncthreads();
        #pragma unroll
        for (int kk = 0; kk < 8; ++kk) {
            float a[8], b[8];
            *(float4*)&a[0] = *(const float4*)&As[kk][ty * 8];
            *(float4*)&a[4] = *(const float4*)&As[kk][ty * 8 + 4];
            *(float4*)&b[0] = *(const float4*)&Bs[kk][tx * 8];
            *(float4*)&b[4] = *(const float4*)&Bs[kk][tx * 8 + 4];
            #pragma unroll
            for (int i = 0; i < 8; ++i)
                #pragma unroll
                for (int j = 0; j < 8; ++j)
                    acc[i][j] = fmaf(a[i], b[j], acc[i][j]);
        }
    }
    float bb[8];
    #pragma unroll
    for (int j = 0; j < 8; ++j) bb[j] = b_in[n0 + tx * 8 + j];
    #pragma unroll
    for (int i = 0; i < 8; ++i) {
        size_t row = (size_t)(m0 + ty * 8 + i) * RR + n0 + tx * 8;
        float4 v0, v1;
        v0.x = acc[i][0] + bb[0]; v0.y = acc[i][1] + bb[1];
        v0.z = acc[i][2] + bb[2]; v0.w = acc[i][3] + bb[3];
        v1.x = acc[i][4] + bb[4]; v1.y = acc[i][5] + bb[5];
        v1.z = acc[i][6] + bb[6]; v1.w = acc[i][7] + bb[7];
        *(float4*)&drive[row] = v0;
        *(float4*)&drive[row + 4] = v1;
    }
}

// ---------------- recurrent scan: 512 blocks x 4 INDEPENDENT waves ----------------
// Wave = (batch b, 64-col group g). No __syncthreads in the T loop: each wave builds
// its own spike list (64 lanes = 64 mask words), stores its own u64 mask word, and
// publishes one bit of a u32 flag (release fetch_or); consumers poll relaxed.
// cg = blk&7 keeps a 1 KB gather window per XCD slice -> L2-resident; per-row XOR
// swizzle (baked into list entries) spreads L2 channels.
// NUMERICS: per-(b,col) chain = drive-first + ascending-row adds + V=fma(BETA,V,acc).
__global__ __launch_bounds__(256, 2) void k_scan(const float* __restrict__ w_rec,
                                                 const float* __restrict__ drive,
                                                 unsigned long long* mask,
                                                 uint32_t* flags, uint32_t* cnts) {
    __shared__ __align__(16) int s_list[4 * RR];   // per-wave private lists, 32 KB

    const int tid = threadIdx.x;
    const int blk = blockIdx.x;       // 0..511
    const int cg = blk & 7;           // col-group-of-8 -> XCD (blockIdx %8 round-robin)
    const int b = blk >> 3;           // batch 0..63
    const int w = tid >> 6;           // wave id 0..3
    const int lane = tid & 63;
    const int g = cg * 4 + w;         // 64-col group 0..31
    const int col = (g << 6) + lane;
    int* wl = &s_list[w << 11];
    const char* Wp = (const char*)w_rec + (lane << 2);
    const uint32_t fbit = 1u << g;

    float V = 0.f;
    uint32_t scnt = 0;
    float dv = drive[(size_t)b * RR + col];   // t = 0

    for (int t = 0; t < TT; ++t) {
        float a = dv;                 // start from drive (bit-exact chain order)
        if (t > 0) {
            const uint32_t* fl = &flags[(t - 1) * BB + b];
            while (__hip_atomic_load(fl, __ATOMIC_RELAXED, __HIP_MEMORY_SCOPE_AGENT)
                   != 0xFFFFFFFFu)
                __builtin_amdgcn_s_sleep(1);
            asm volatile("" ::: "memory");   // no hoisting of mask read above poll
            // wave-private list build: lane i holds mask word i (32 bits)
            uint32_t m = __hip_atomic_load(
                (const uint32_t*)(mask + (size_t)((t - 1) * BB + b) * 32) + lane,
                __ATOMIC_RELAXED, __HIP_MEMORY_SCOPE_AGENT);
            int p = __popc(m);
            int off = p;
            #pragma unroll
            for (int d = 1; d < 64; d <<= 1) {
                int o = __shfl_up(off, d);
                if (lane >= d) off += o;
            }
            const int n = __shfl(off, 63);
            int e = off - p;
            int base = lane << 5;
            while (m) {
                int bit = __builtin_ctz(m);
                m &= m - 1;
                int row = base + bit;
                // byte offset with per-row XOR swizzle baked in (g constant per wave)
                wl[e++] = (row << 13) | ((((row & 31) ^ g)) << 8);
            }
            __threadfence_block();    // drain ds_writes before cross-lane ds_reads
            int i = 0;
            for (; i + 32 <= n; i += 32) {
                int4 o[8];
                #pragma unroll
                for (int j = 0; j < 8; ++j) o[j] = *(const int4*)&wl[i + 4 * j];
                float v[32];
                #pragma unroll
                for (int j = 0; j < 8; ++j) {
                    v[4 * j + 0] = *(const float*)(Wp + o[j].x);
                    v[4 * j + 1] = *(const float*)(Wp + o[j].y);
                    v[4 * j + 2] = *(const float*)(Wp + o[j].z);
                    v[4 * j + 3] = *(const float*)(Wp + o[j].w);
                }
                #pragma unroll
                for (int j = 0; j < 32; ++j) a += v[j];    // ascending order
            }
            for (; i + 8 <= n; i += 8) {
                int4 o0 = *(const int4*)&wl[i];
                int4 o1 = *(const int4*)&wl[i + 4];
                float v0 = *(const float*)(Wp + o0.x);
                float v1 = *(const float*)(Wp + o0.y);
                float v2 = *(const float*)(Wp + o0.z);
                float v3 = *(const float*)(Wp + o0.w);
                float v4 = *(const float*)(Wp + o1.x);
                float v5 = *(const float*)(Wp + o1.y);
                float v6 = *(const float*)(Wp + o1.z);
                float v7 = *(const float*)(Wp + o1.w);
                a += v0; a += v1; a += v2; a += v3;
                a += v4; a += v5; a += v6; a += v7;
            }
            for (; i < n; ++i) a += *(const float*)(Wp + wl[i]);
        }

        V = BETA * V + a;             // fma(BETA, V, drive + ascending sum)
        bool sp = V > VTH;
        if (sp) V -= VTH;

        if (t + 1 < TT)   // prefetch next drive (independent of spikes)
            dv = drive[(size_t)(t + 1) * (BB * RR) + (size_t)b * RR + col];

        unsigned long long bal = __ballot(sp);   // this wave's 64 cols
        if (lane == 0) {
            __hip_atomic_store(mask + (size_t)(t * BB + b) * 32 + g, bal,
                               __ATOMIC_RELAXED, __HIP_MEMORY_SCOPE_AGENT);
            scnt += (uint32_t)__popcll(bal);
            // release RMW: orders the mask store before the flag bit becomes visible
            (void)__hip_atomic_fetch_or(&flags[t * BB + b], fbit,
                                        __ATOMIC_RELEASE, __HIP_MEMORY_SCOPE_AGENT);
        }
    }

    if (lane == 0 && scnt) atomicAdd(&cnts[0], scnt);
}

// ---------------- head: logits[t,b,:] = s @ w_head + b_head (sparse gather) ----------------
__global__ __launch_bounds__(128) void k_head(const uint32_t* __restrict__ mask,
                                              const float* __restrict__ w_head,
                                              const float* __restrict__ b_head,
                                              float* __restrict__ logits) {
    __shared__ uint32_t sm[64];
    int tb = blockIdx.x;        // t*64 + b
    int tid = threadIdx.x;      // 0..127
    if (tid < 64) sm[tid] = mask[tb * 64 + tid];
    __syncthreads();
    float acc = b_head[tid];
    for (int w = 0; w < 64; ++w) {
        uint32_t m = sm[w];     // uniform per block -> no divergence
        int base = w << 5;
        while (m) {
            int bit = __builtin_ctz(m);
            m &= m - 1;
            acc += w_head[(size_t)(base + bit) * DOUT + tid];
        }
    }
    logits[(size_t)tb * DOUT + tid] = acc;
}

__global__ __launch_bounds__(128) void k_readout(const float* __restrict__ logits,
                                                 float* __restrict__ readout) {
    int b = blockIdx.x, cidx = threadIdx.x;
    float s = 0.0f;
    for (int t = 0; t < TT; ++t)
        s += logits[(size_t)t * (BB * DOUT) + b * DOUT + cidx];
    readout[b * DOUT + cidx] = s * (1.0f / (float)TT);
}

__global__ void k_scalars(const uint32_t* __restrict__ cnts, float* __restrict__ out) {
    if (threadIdx.x == 0 && blockIdx.x == 0) {
        out[BB * DOUT + TT * BB * DOUT]     = (float)cnts[0] / (float)(TT * BB * RR);
        out[BB * DOUT + TT * BB * DOUT + 1] = (float)cnts[1] / (float)NTOT;
    }
}

extern "C" void kernel_launch(void* const* d_in, const int* in_sizes, int n_in,
                              void* d_out, int out_size, void* d_ws, size_t ws_size,
                              hipStream_t stream) {
    const float* x      = (const float*)d_in[0];
    const float* w_in   = (const float*)d_in[1];
    const float* b_in   = (const float*)d_in[2];
    float*       w_rec  = (float*)d_in[3];        // masked+swizzled in place
    const float* w_head = (const float*)d_in[4];
    const float* b_head = (const float*)d_in[5];
    float* out = (float*)d_out;

    float*    drive = (float*)d_ws;
    unsigned long long* mask = (unsigned long long*)((char*)d_ws + 134217728u);
    uint32_t* flags = (uint32_t*)(mask + (size_t)TT * BB * 32);
    uint32_t* hist  = flags + TT * BB;
    uint32_t* state = hist + 256;
    uint32_t* cnts  = state + 8;

    // zero flags + hist + state + cnts (mask words fully overwritten before read)
    k_init<<<64, 256, 0, stream>>>(flags, TT * BB + 256 + 8 + 2);

    for (int p = 0; p < 4; ++p) {
        k_hist<<<1024, 256, 0, stream>>>(w_rec, hist, state, p);
        k_select<<<1, 256, 0, stream>>>(hist, state, p);
    }
    k_swz<<<RR, 1024, 0, stream>>>(w_rec, state, cnts);

    k_drive<<<dim3(128, 16), 256, 0, stream>>>(x, w_in, b_in, drive);

    k_scan<<<512, 256, 0, stream>>>(w_rec, drive, mask, flags, cnts);

    k_head<<<TT * BB, 128, 0, stream>>>((const uint32_t*)mask, w_head, b_head,
                                        out + BB * DOUT);
    k_readout<<<BB, 128, 0, stream>>>(out + BB * DOUT, out);
    k_scalars<<<1, 64, 0, stream>>>(cnts, out);
}

// Round 8
// 5425.171 us; speedup vs baseline: 2.7354x; 2.7354x over previous
//
#include <hip/hip_runtime.h>
#include <hip/hip_bf16.h>
#include <stdint.h>

// Problem constants
#define TT 256
#define BB 64
#define DIN 512
#define RR 2048
#define DOUT 128
#define NTOT (RR*RR)                // 4194304
#define NKEEP 838860                // int(4194304 * (1.0 - 0.8)) in IEEE double
#define BETA 0.9f
#define VTH 1.0f

// ---------------- workspace layout ----------------
// drive : float [16384][2048]   @ 0            (134217728 B)
// mask  : u32   [256][64][64]   @ 134217728    (4 MB)  spike bitmask per (t,b)
// flags : u64   [256][64]       @ +4MB         (128 KB) 8 producer bytes per (t,b)
// hist  : u32   [256]
// state : u32   [8]   (0: prefix, 1: remaining, 2: thresh bits)
// cnts  : u32   [2]   (0: spike count, 1: active count)
// NOTE: w_rec is masked AND sub-window-swizzled IN PLACE (inputs restored each launch).
//       Row r, 1KB chunk cg: 256B sub-window w's data lives at sub-window w ^ (r & 3).
//       Swizzle stays INSIDE the chunk -> each XCD's 2MB slice residency is preserved.

__global__ void k_init(uint32_t* __restrict__ p, int n) {
    int i = blockIdx.x * blockDim.x + threadIdx.x;
    int stride = gridDim.x * blockDim.x;
    for (; i < n; i += stride) p[i] = 0u;
}

// ---------------- radix select (4 passes x 8 bits, k-th largest) ----------------
__global__ void k_hist(const float* __restrict__ w_rec, uint32_t* __restrict__ hist,
                       const uint32_t* __restrict__ state, int p) {
    __shared__ uint32_t lh[256];
    lh[threadIdx.x] = 0u;
    __syncthreads();
    uint32_t prefix = (p > 0) ? state[0] : 0u;
    int sh = 24 - 8 * p;
    int i = blockIdx.x * 256 + threadIdx.x;
    int stride = gridDim.x * 256;
    for (; i < NTOT; i += stride) {
        uint32_t u = __float_as_uint(fabsf(w_rec[i]));
        bool ok = (p == 0) || ((u >> (sh + 8)) == prefix);
        if (ok) atomicAdd(&lh[(u >> sh) & 255u], 1u);
    }
    __syncthreads();
    uint32_t v = lh[threadIdx.x];
    if (v) atomicAdd(&hist[threadIdx.x], v);
}

__global__ void k_select(uint32_t* __restrict__ hist, uint32_t* __restrict__ state, int p) {
    __shared__ uint32_t lh[256];
    int tid = threadIdx.x;
    lh[tid] = hist[tid];
    hist[tid] = 0u;            // ready for next pass
    __syncthreads();
    if (tid == 0) {
        uint32_t remaining = (p == 0) ? (uint32_t)NKEEP : state[1];
        int bin = 255;
        for (; bin > 0; --bin) {
            uint32_t c = lh[bin];
            if (c >= remaining) break;
            remaining -= c;
        }
        uint32_t pref = (p == 0) ? 0u : state[0];
        pref = (pref << 8) | (uint32_t)bin;
        state[0] = pref;
        state[1] = remaining;
        if (p == 3) state[2] = pref;   // full 32-bit pattern of threshold value
    }
}

// ---- fused: mask + count + sub-window swizzle (involution w^=(r&3) inside 1KB chunks) ----
__global__ __launch_bounds__(1024) void k_swz(float* __restrict__ w,
                                              const uint32_t* __restrict__ state,
                                              uint32_t* __restrict__ cnts) {
    const int r = blockIdx.x;          // row 0..2047
    const uint32_t th = state[2];
    const int m = r & 3;
    const int tid = threadIdx.x;       // 0..1023
    uint32_t c = 0;
    if (m == 0) {
        #pragma unroll
        for (int q = 0; q < 2; ++q) {
            size_t i = (size_t)r * RR + q * 1024 + tid;
            float v = w[i];
            if ((__float_as_uint(v) & 0x7fffffffu) >= th) c++;
            else w[i] = 0.0f;
        }
    } else {
        const int h = (m == 1) ? 0 : 1;        // MSB index of m (m in 1..3)
        const int chunk = tid >> 7;            // 0..7 (1 KB chunks = cg windows)
        const int pair = (tid >> 6) & 1;       // 0..1
        const int lane = tid & 63;
        const int g  = (h == 0) ? (pair << 1) : pair;   // sub-window with bit h clear
        const int g2 = g ^ m;
        const size_t i1 = (size_t)r * RR + chunk * 256 + g  * 64 + lane;
        const size_t i2 = (size_t)r * RR + chunk * 256 + g2 * 64 + lane;
        float v1 = w[i1], v2 = w[i2];
        if ((__float_as_uint(v1) & 0x7fffffffu) >= th) c++; else v1 = 0.0f;
        if ((__float_as_uint(v2) & 0x7fffffffu) >= th) c++; else v2 = 0.0f;
        w[i1] = v2;                    // involution swap
        w[i2] = v1;
    }
    for (int off = 32; off > 0; off >>= 1) c += __shfl_down(c, off);
    if ((tid & 63) == 0 && c) atomicAdd(&cnts[1], c);
}

// ---------------- drive GEMM: [16384,512] x [512,2048] + b_in ----------------
__global__ __launch_bounds__(256) void k_drive(const float* __restrict__ x,
                                               const float* __restrict__ w_in,
                                               const float* __restrict__ b_in,
                                               float* __restrict__ drive) {
    __shared__ float As[8][128];
    __shared__ float Bs[8][128];
    const int m0 = blockIdx.x * 128;
    const int n0 = blockIdx.y * 128;
    const int tid = threadIdx.x;
    const int tx = tid & 15, ty = tid >> 4;
    const int ar = tid >> 1;
    const int ak = (tid & 1) * 4;
    const int bk = tid >> 5;
    const int bc = (tid & 31) * 4;
    float acc[8][8];
    #pragma unroll
    for (int i = 0; i < 8; ++i)
        #pragma unroll
        for (int j = 0; j < 8; ++j) acc[i][j] = 0.0f;

    for (int k0 = 0; k0 < DIN; k0 += 8) {
        float4 av = *(const float4*)&x[(m0 + ar) * DIN + k0 + ak];
        float4 bv = *(const float4*)&w_in[(size_t)(k0 + bk) * RR + n0 + bc];
        __syncthreads();
        As[ak + 0][ar] = av.x; As[ak + 1][ar] = av.y;
        As[ak + 2][ar] = av.z; As[ak + 3][ar] = av.w;
        *(float4*)&Bs[bk][bc] = bv;
        __syncthreads();
        #pragma unroll
        for (int kk = 0; kk < 8; ++kk) {
            float a[8], b[8];
            *(float4*)&a[0] = *(const float4*)&As[kk][ty * 8];
            *(float4*)&a[4] = *(const float4*)&As[kk][ty * 8 + 4];
            *(float4*)&b[0] = *(const float4*)&Bs[kk][tx * 8];
            *(float4*)&b[4] = *(const float4*)&Bs[kk][tx * 8 + 4];
            #pragma unroll
            for (int i = 0; i < 8; ++i)
                #pragma unroll
                for (int j = 0; j < 8; ++j)
                    acc[i][j] = fmaf(a[i], b[j], acc[i][j]);
        }
    }
    float bb[8];
    #pragma unroll
    for (int j = 0; j < 8; ++j) bb[j] = b_in[n0 + tx * 8 + j];
    #pragma unroll
    for (int i = 0; i < 8; ++i) {
        size_t row = (size_t)(m0 + ty * 8 + i) * RR + n0 + tx * 8;
        float4 v0, v1;
        v0.x = acc[i][0] + bb[0]; v0.y = acc[i][1] + bb[1];
        v0.z = acc[i][2] + bb[2]; v0.w = acc[i][3] + bb[3];
        v1.x = acc[i][4] + bb[4]; v1.y = acc[i][5] + bb[5];
        v1.z = acc[i][6] + bb[6]; v1.w = acc[i][7] + bb[7];
        *(float4*)&drive[row] = v0;
        *(float4*)&drive[row + 4] = v1;
    }
}

// ---------------- recurrent scan: 512 blocks = 64 batches x 8 col-groups ----------------
// Round-6 structure (best known): block = (batch b, 256-col group cg), cg = blk&7 keeps
// the 2 MB w_rec slice on one XCD; wave0 builds the shared ascending spike list; all 4
// waves gather coalesced 256 B windows. Deltas vs round 6:
//   * per-row sub-window swizzle (w ^ (r&3)) baked into list entries; wave XORs (w<<8)
//     into the OFFSET -> L2 channel bits vary per row, slice residency preserved.
//   * 32-deep load batches (8 KB in flight/wave), launch_bounds(256,2) caps VGPR<=128
//     so 2 blocks/CU residency (deadlock-freedom) is guaranteed.
// SYNC: relaxed polls only; release byte-store publish (round-6 protocol, proven).
// NUMERICS: per-(b,col) chain = drive-first + ascending-row adds + V=fma(BETA,V,acc).
__global__ __launch_bounds__(256, 2) void k_scan(const float* __restrict__ w_rec,
                                                 const float* __restrict__ drive,
                                                 uint32_t* mask, unsigned long long* flags,
                                                 uint32_t* cnts) {
    __shared__ __align__(16) int s_list[RR];   // entries: (row<<13)|((row&3)<<8), 8 KB
    __shared__ int s_n;
    __shared__ uint32_t s_red[4];

    const int tid = threadIdx.x;
    const int blk = blockIdx.x;       // 0..511
    const int cg = blk & 7;           // col-group -> XCD (blockIdx %8 round-robin)
    const int b = blk >> 3;           // batch 0..63
    const int w = tid >> 6;           // wave id 0..3 (= logical 256B sub-window)
    const int lane = tid & 63;
    const int col = (cg << 8) + tid;  // logical column (drive/ballot indexing)
    const int wx = w << 8;            // XOR constant for swizzled sub-window offset
    const char* Wq = (const char*)w_rec + (cg << 10) + (lane << 2);

    float V = 0.f;
    uint32_t scnt = 0;
    float dv = drive[(size_t)b * RR + col];   // t = 0

    for (int t = 0; t < TT; ++t) {
        float a = dv;                 // start from drive (bit-exact chain order)
        if (t > 0) {
            if (tid == 0) {
                const unsigned long long* fl = &flags[(size_t)(t - 1) * BB + b];
                while (__hip_atomic_load(fl, __ATOMIC_RELAXED, __HIP_MEMORY_SCOPE_AGENT)
                       != ~0ull)
                    __builtin_amdgcn_s_sleep(1);
            }
            __syncthreads();
            if (tid < 64) {   // wave 0: load batch mask, build ascending spike list
                uint32_t m = __hip_atomic_load(&mask[((size_t)(t - 1) * BB + b) * 64 + tid],
                                               __ATOMIC_RELAXED, __HIP_MEMORY_SCOPE_AGENT);
                int p = __popc(m);
                int off = p;
                #pragma unroll
                for (int d = 1; d < 64; d <<= 1) {
                    int o = __shfl_up(off, d);
                    if (tid >= d) off += o;
                }
                if (tid == 63) s_n = off;
                int e = off - p;
                int base = tid << 5;
                while (m) {
                    int bit = __builtin_ctz(m);
                    m &= m - 1;
                    int row = base + bit;
                    s_list[e++] = (row << 13) | ((row & 3) << 8);
                }
            }
            __syncthreads();
            const int n = s_n;
            int i = 0;
            for (; i + 32 <= n; i += 32) {
                int4 o[8];
                #pragma unroll
                for (int j = 0; j < 8; ++j) o[j] = *(const int4*)&s_list[i + 4 * j];
                float v[32];
                #pragma unroll
                for (int j = 0; j < 8; ++j) {
                    v[4 * j + 0] = *(const float*)(Wq + (o[j].x ^ wx));
                    v[4 * j + 1] = *(const float*)(Wq + (o[j].y ^ wx));
                    v[4 * j + 2] = *(const float*)(Wq + (o[j].z ^ wx));
                    v[4 * j + 3] = *(const float*)(Wq + (o[j].w ^ wx));
                }
                #pragma unroll
                for (int j = 0; j < 32; ++j) a += v[j];    // ascending order
            }
            for (; i + 8 <= n; i += 8) {
                int4 o0 = *(const int4*)&s_list[i];
                int4 o1 = *(const int4*)&s_list[i + 4];
                float v0 = *(const float*)(Wq + (o0.x ^ wx));
                float v1 = *(const float*)(Wq + (o0.y ^ wx));
                float v2 = *(const float*)(Wq + (o0.z ^ wx));
                float v3 = *(const float*)(Wq + (o0.w ^ wx));
                float v4 = *(const float*)(Wq + (o1.x ^ wx));
                float v5 = *(const float*)(Wq + (o1.y ^ wx));
                float v6 = *(const float*)(Wq + (o1.z ^ wx));
                float v7 = *(const float*)(Wq + (o1.w ^ wx));
                a += v0; a += v1; a += v2; a += v3;
                a += v4; a += v5; a += v6; a += v7;
            }
            for (; i < n; ++i) a += *(const float*)(Wq + (s_list[i] ^ wx));
        }

        V = BETA * V + a;             // fma(BETA, V, drive + ascending sum)
        bool sp = V > VTH;
        if (sp) V -= VTH;

        if (t + 1 < TT)   // prefetch next drive (independent of spikes)
            dv = drive[((size_t)(t + 1) * BB + b) * RR + col];

        unsigned long long bal = __ballot(sp);   // 64 logical cols of this wave
        if (lane == 0) {
            // u64 mask word (cg*4 + w) covers neurons [cg*256 + w*64, +64)
            __hip_atomic_store(
                (unsigned long long*)&mask[((size_t)t * BB + b) * 64] + (cg * 4 + w),
                bal, __ATOMIC_RELAXED, __HIP_MEMORY_SCOPE_AGENT);
            scnt += (uint32_t)__popcll(bal);
        }
        __syncthreads();   // drains all 4 waves' mask stores (vmcnt(0) before barrier)
        if (tid == 0)      // release: publish flag byte cg for (t,b)
            __hip_atomic_store((uint8_t*)&flags[(size_t)t * BB + b] + cg, (uint8_t)0xFF,
                               __ATOMIC_RELEASE, __HIP_MEMORY_SCOPE_AGENT);
    }

    if (lane == 0) s_red[w] = scnt;
    __syncthreads();
    if (tid == 0) {
        uint32_t s = s_red[0] + s_red[1] + s_red[2] + s_red[3];
        if (s) atomicAdd(&cnts[0], s);
    }
}

// ---------------- head: logits[t,b,:] = s @ w_head + b_head (sparse gather) ----------------
__global__ __launch_bounds__(128) void k_head(const uint32_t* __restrict__ mask,
                                              const float* __restrict__ w_head,
                                              const float* __restrict__ b_head,
                                              float* __restrict__ logits) {
    __shared__ uint32_t sm[64];
    int tb = blockIdx.x;        // t*64 + b
    int tid = threadIdx.x;      // 0..127
    if (tid < 64) sm[tid] = mask[tb * 64 + tid];
    __syncthreads();
    float acc = b_head[tid];
    for (int w = 0; w < 64; ++w) {
        uint32_t m = sm[w];     // uniform per block -> no divergence
        int base = w << 5;
        while (m) {
            int bit = __builtin_ctz(m);
            m &= m - 1;
            acc += w_head[(size_t)(base + bit) * DOUT + tid];
        }
    }
    logits[(size_t)tb * DOUT + tid] = acc;
}

__global__ __launch_bounds__(128) void k_readout(const float* __restrict__ logits,
                                                 float* __restrict__ readout) {
    int b = blockIdx.x, cidx = threadIdx.x;
    float s = 0.0f;
    for (int t = 0; t < TT; ++t)
        s += logits[(size_t)t * (BB * DOUT) + b * DOUT + cidx];
    readout[b * DOUT + cidx] = s * (1.0f / (float)TT);
}

__global__ void k_scalars(const uint32_t* __restrict__ cnts, float* __restrict__ out) {
    if (threadIdx.x == 0 && blockIdx.x == 0) {
        out[BB * DOUT + TT * BB * DOUT]     = (float)cnts[0] / (float)(TT * BB * RR);
        out[BB * DOUT + TT * BB * DOUT + 1] = (float)cnts[1] / (float)NTOT;
    }
}

extern "C" void kernel_launch(void* const* d_in, const int* in_sizes, int n_in,
                              void* d_out, int out_size, void* d_ws, size_t ws_size,
                              hipStream_t stream) {
    const float* x      = (const float*)d_in[0];
    const float* w_in   = (const float*)d_in[1];
    const float* b_in   = (const float*)d_in[2];
    float*       w_rec  = (float*)d_in[3];        // masked+swizzled in place
    const float* w_head = (const float*)d_in[4];
    const float* b_head = (const float*)d_in[5];
    float* out = (float*)d_out;

    float*    drive = (float*)d_ws;
    uint32_t* mask  = (uint32_t*)((char*)d_ws + 134217728u);
    unsigned long long* flags = (unsigned long long*)(mask + (TT * BB * 64));
    uint32_t* hist  = (uint32_t*)(flags + TT * BB);
    uint32_t* state = hist + 256;
    uint32_t* cnts  = state + 8;

    // zero flags + hist + state + cnts (mask fully overwritten before read)
    k_init<<<64, 256, 0, stream>>>((uint32_t*)flags, TT * BB * 2 + 256 + 8 + 2);

    for (int p = 0; p < 4; ++p) {
        k_hist<<<1024, 256, 0, stream>>>(w_rec, hist, state, p);
        k_select<<<1, 256, 0, stream>>>(hist, state, p);
    }
    k_swz<<<RR, 1024, 0, stream>>>(w_rec, state, cnts);

    k_drive<<<dim3(128, 16), 256, 0, stream>>>(x, w_in, b_in, drive);

    k_scan<<<512, 256, 0, stream>>>(w_rec, drive, mask, flags, cnts);

    k_head<<<TT * BB, 128, 0, stream>>>(mask, w_head, b_head, out + BB * DOUT);
    k_readout<<<BB, 128, 0, stream>>>(out + BB * DOUT, out);
    k_scalars<<<1, 64, 0, stream>>>(cnts, out);
}